// Round 9
// baseline (156.717 us; speedup 1.0000x reference)
//
#include <hip/hip_runtime.h>
#include <math.h>

typedef unsigned int uint;
typedef unsigned short ushort;
typedef unsigned char uchar;
typedef unsigned long ulong_;
typedef __attribute__((ext_vector_type(4))) float f32x4;

// Problem constants
#define BB  16384
#define DD  64
#define NT_ 128
#define NZ_ 2048
#define NJ_ 2049   // NZ+1

// workspace layout (float offsets) — all regions disjoint (R6 lesson: verify
// end offsets; wzbp8 is 131072 BYTES = 32768 floats).
#define BIAS_OFF 0         // fp32 [64]                        -> end 64
#define IL2_OFF  64        // il2[c] = exp(-2 lsz)*log2e [2048]  -> end 2112
#define A0_OFF   2112      // a0[c]  = -cc * il2          [2048] -> end 4160
#define NIQ_OFF  4160      // niq[c] = -inv * q           [2048] -> end 6208
#define INV_OFF  6208      // inv[c] = exp(-2 lsz)        [2048] -> end 8256
#define CZ8A_OFF 8256      // fp8 cz k0 [NZ][32] = 16384 floats  -> end 24640
#define CZ8B_OFF 24640     // fp8 cz k1                          -> end 41024
#define WZ8A_OFF 41024     // fp8 WzT k0                         -> end 57408
#define WZ8B_OFF 57408     // fp8 WzT k1                         -> end 73792
#define WZBP_OFF 73792     // fp8 Wz packed [64][64][32]B = 32768 floats -> end 106560
#define PART_OFF 106560    // fp32 partials [4][64][NJ_] = 524544 -> end 631104
// end 631104 floats ~= 2.52 MB

// ---------------- fp8 e4m3 (OCP) conversion helpers ----------------
#if __has_builtin(__builtin_amdgcn_cvt_pk_fp8_f32)
__device__ __forceinline__ uint pk4_fp8(float a, float b, float c, float d) {
  int v = __builtin_amdgcn_cvt_pk_fp8_f32(a, b, 0, false);
  v = __builtin_amdgcn_cvt_pk_fp8_f32(c, d, v, true);
  return (uint)v;
}
__device__ __forceinline__ uchar f8_1(float x) {
  return (uchar)(__builtin_amdgcn_cvt_pk_fp8_f32(x, x, 0, false) & 0xFF);
}
#else
__device__ __forceinline__ uint sw_f8(float x) {
  uint u = __float_as_uint(x);
  uint s = (u >> 24) & 0x80u;
  float ax = __uint_as_float(u & 0x7FFFFFFFu);
  if (!(ax >= 0.015625f)) return s;          // flush tiny / NaN -> signed zero
  if (ax >= 448.f) return s | 0x7Eu;
  uint q = __float_as_uint(ax);
  q += 0x7FFFFu + ((q >> 20) & 1u);          // RNE at mantissa bit 20
  uint e = (q >> 23) - 120u;                 // rebias (127 -> 7)
  return s | ((e & 0xFu) << 3) | ((q >> 20) & 7u);
}
__device__ __forceinline__ uchar f8_1(float x) { return (uchar)sw_f8(x); }
__device__ __forceinline__ uint pk4_fp8(float a, float b, float c, float d) {
  return sw_f8(a) | (sw_f8(b) << 8) | (sw_f8(c) << 16) | (sw_f8(d) << 24);
}
#endif

// ---------------------------------------------------------------------------
// Kernel 1 (stage 1): split-K partial sums of W_t = einsum('dij,i->dj').
// 2304 blocks (9/CU, 32 waves/CU) -> latency-tolerant W read (67 MB, BW-bound,
// ~5.2 TB/s, near the 10.6us floor). R2: fewer waves/CU collapses to 330 GB/s.
__global__ __launch_bounds__(256) void k_wt1(
    const float* __restrict__ t, const float* __restrict__ ct,
    const float* __restrict__ lst, const float* __restrict__ W,
    float* __restrict__ part)   // [4][64][NJ_]
{
  __shared__ float ph[32];
  int tx = threadIdx.x;
  int d  = blockIdx.y;
  int ic = blockIdx.z;
  if (tx < 32) {
    int i = ic * 32 + tx;
    float r = fabsf(t[0] - ct[i]) * __expf(-lst[i]);
    ph[tx] = __expf(-r * r);
  }
  __syncthreads();
  int j = blockIdx.x * 256 + tx;
  if (j >= NJ_) return;
  const float* Wp = W + (size_t)d * NT_ * NJ_ + (size_t)(ic * 32) * NJ_ + j;
  float acc = 0.f;
#pragma unroll
  for (int k = 0; k < 32; ++k) acc += Wp[(size_t)k * NJ_] * ph[k];
  part[((size_t)ic * 64 + d) * NJ_ + j] = acc;
}

// ---------------------------------------------------------------------------
// Kernel 2 (stage 2): 256 blocks x 256 thr, 8 centres/block.
// Emits PLANAR per-centre constants {il2, a0, niq, inv} (inv added R9 so the
// hot loop's g = fma(d2, inv, nq) needs no per-element recompute of inv).
__global__ __launch_bounds__(256) void k_prep2(
    const float* __restrict__ part, const float* __restrict__ cz,
    const float* __restrict__ lsz,
    float* __restrict__ bias,
    float* __restrict__ il2a, float* __restrict__ a0a, float* __restrict__ niqa,
    float* __restrict__ inva,
    uchar* __restrict__ cz8a, uchar* __restrict__ cz8b,
    uchar* __restrict__ wz8a, uchar* __restrict__ wz8b,
    uchar* __restrict__ wzbp8)
{
  __shared__ float wt[64][9];   // [d][c_local]
  int tid = threadIdx.x;
  int cb0 = blockIdx.x * 8;
#pragma unroll
  for (int h = 0; h < 2; ++h) {
    int f = h * 256 + tid;      // 512 = 64 d x 8 c
    int d = f >> 3, c = f & 7;
    size_t idx = (size_t)d * NJ_ + cb0 + c;
    float s = part[idx] + part[(size_t)64 * NJ_ + idx]
            + part[(size_t)128 * NJ_ + idx] + part[(size_t)192 * NJ_ + idx];
    wt[d][c] = s;
    int cg = cb0 + c;
    wzbp8[((size_t)(cg >> 5) * 64 + d) * 32 + (cg & 31)] = f8_1(s);
  }
  if (blockIdx.x == 0 && tid < 64) {
    size_t idx = (size_t)tid * NJ_ + 2048;
    bias[tid] = part[idx] + part[(size_t)64 * NJ_ + idx]
              + part[(size_t)128 * NJ_ + idx] + part[(size_t)192 * NJ_ + idx];
  }
  __syncthreads();
  int cl = tid >> 5;            // centre within block 0..7
  int k  = tid & 31;            // 0..31
  int c  = cb0 + cl;
  float cv0 = cz[(size_t)c * DD + k];
  float cv1 = cz[(size_t)c * DD + 32 + k];
  cz8a[(size_t)c * 32 + k] = f8_1(cv0);
  cz8b[(size_t)c * 32 + k] = f8_1(cv1);
  float w0 = wt[k][cl], w1 = wt[32 + k][cl];
  wz8a[(size_t)c * 32 + k] = f8_1(w0);
  wz8b[(size_t)c * 32 + k] = f8_1(w1);
  float ca = cv0 * cv0 + cv1 * cv1;
  float qa = w0 * cv0 + w1 * cv1;
  qa += __shfl_xor(qa, 1);  ca += __shfl_xor(ca, 1);
  qa += __shfl_xor(qa, 2);  ca += __shfl_xor(ca, 2);
  qa += __shfl_xor(qa, 4);  ca += __shfl_xor(ca, 4);
  qa += __shfl_xor(qa, 8);  ca += __shfl_xor(ca, 8);
  qa += __shfl_xor(qa, 16); ca += __shfl_xor(ca, 16);
  if (k == 0) {
    float inv = __expf(-2.f * lsz[c]);
    float il2 = inv * 1.44269504f;     // inv * log2e
    il2a[c] = il2;
    a0a[c]  = -ca * il2;               // -cc * il2
    niqa[c] = -inv * qa;               // -inv * q
    inva[c] = inv;
  }
}

// ---------------------------------------------------------------------------
// Main fused MFMA kernel — R9: BM=16 + grid 1024 + FULL register double-buffer
// + (256,2).
// Synthesis of R7/R8 evidence: the allocator targets 64 VGPR (8 waves/EU)
// unless (256,2) relaxes it — at 64 it either spills (R4) or serializes the
// loads (R8, two exposed L2 latencies per chunk). (256,2) keeps the prefetch
// live (R2: 92 VGPR). BM=16 halves the frag state (~130 VGPR) so 3-4 blocks/CU
// can be co-resident (R7 was grid-limited to 2) — occupancy AND pipeline.
// Swapped-operand GEMM1 + in-register shuffle transpose (R7/R8-proven).
__global__ __launch_bounds__(256, 2) void k_fused(
    const float* __restrict__ z,
    const uchar* __restrict__ cz8a, const uchar* __restrict__ cz8b,
    const uchar* __restrict__ wz8a, const uchar* __restrict__ wz8b,
    const uchar* __restrict__ wzbp8,
    const float* __restrict__ il2a, const float* __restrict__ a0a,
    const float* __restrict__ niqa, const float* __restrict__ inva,
    const float* __restrict__ bias, float* __restrict__ out)
{
  __shared__ float eps[16 * 68];   // dz combine scratch
  __shared__ float dlr[4][16];

  int tid  = threadIdx.x;
  int ws   = tid >> 6;           // wave = c-split group 0..3
  int lane = tid & 63;
  int lrow = lane & 15, quad = lane >> 4;
  int b0 = blockIdx.x * 16;

  // ---- prologue: read fp32 z row, pack fp8 frags + own-row norm ----
  long az[2];
  float nzz;
  {
    const float* zr = z + (size_t)(b0 + lrow) * DD + quad * 8;
    float4 v0 = *(const float4*)zr;
    float4 v1 = *(const float4*)(zr + 4);
    float4 v2 = *(const float4*)(zr + 32);
    float4 v3 = *(const float4*)(zr + 36);
    uint l0 = pk4_fp8(v0.x, v0.y, v0.z, v0.w);
    uint l1 = pk4_fp8(v1.x, v1.y, v1.z, v1.w);
    uint h0 = pk4_fp8(v2.x, v2.y, v2.z, v2.w);
    uint h1 = pk4_fp8(v3.x, v3.y, v3.z, v3.w);
    az[0] = (long)(((ulong_)l1 << 32) | l0);
    az[1] = (long)(((ulong_)h1 << 32) | h0);
    float ss = v0.x * v0.x + v0.y * v0.y + v0.z * v0.z + v0.w * v0.w
             + v1.x * v1.x + v1.y * v1.y + v1.z * v1.z + v1.w * v1.w
             + v2.x * v2.x + v2.y * v2.y + v2.z * v2.z + v2.w * v2.w
             + v3.x * v3.x + v3.y * v3.y + v3.z * v3.z + v3.w * v3.w;
    ss += __shfl_xor(ss, 16);    // combine the 4 quad partials -> full row sum
    ss += __shfl_xor(ss, 32);
    nzz = -ss;                   // own row's -|z|^2
  }

  f32x4 acc[4];
#pragma unroll
  for (int nt = 0; nt < 4; ++nt) acc[nt] = (f32x4){0.f, 0.f, 0.f, 0.f};
  float dl = 0.f;

  const f32x4 zero = (f32x4){0.f, 0.f, 0.f, 0.f};
  int cbase = ws * 512;

  // ---- register double-buffered prefetch state (fp8 frags only) ----
  long Abc0[2][2], Abc1[2][2], Abw0[2][2], Abw1[2][2], Abb[2][4];
#define LOADB(PAR, C0)                                                         \
  do {                                                                         \
    int c0_ = (C0);                                                            \
    _Pragma("unroll")                                                          \
    for (int nt = 0; nt < 2; ++nt) {                                           \
      int cg_ = c0_ + nt * 16 + lrow;                                          \
      size_t ro_ = (size_t)cg_ * 32 + quad * 8;                                \
      Abc0[PAR][nt] = *(const long*)(cz8a + ro_);                              \
      Abc1[PAR][nt] = *(const long*)(cz8b + ro_);                              \
      Abw0[PAR][nt] = *(const long*)(wz8a + ro_);                              \
      Abw1[PAR][nt] = *(const long*)(wz8b + ro_);                              \
    }                                                                          \
    size_t cb_ = (size_t)(c0_ >> 5) * 64 * 32;                                 \
    _Pragma("unroll")                                                          \
    for (int nt = 0; nt < 4; ++nt)                                             \
      Abb[PAR][nt] =                                                           \
          *(const long*)(wzbp8 + cb_ + (size_t)(nt * 16 + lrow) * 32 + quad * 8); \
  } while (0)

  LOADB(0, cbase);
#pragma unroll 2
  for (int it = 0; it < 16; ++it) {
    int par = it & 1;
    int c0  = cbase + it * 32;

    // current-chunk planar constants; consumed after GEMM1 (latency covered)
    float4 ilv[2], a0v[2], nqv[2], ivv[2];
#pragma unroll
    for (int nt = 0; nt < 2; ++nt) {
      int cb = c0 + nt * 16 + quad * 4;
      ilv[nt] = *(const float4*)&il2a[cb];
      a0v[nt] = *(const float4*)&a0a[cb];
      nqv[nt] = *(const float4*)&niqa[cb];
      ivv[nt] = *(const float4*)&inva[cb];
    }

    // ---- GEMM1 (swapped): thread owns row lrow, c = c0+nt*16+quad*4+i ----
    f32x4 d1a[2], d2a[2];
#pragma unroll
    for (int nt = 0; nt < 2; ++nt) {
      f32x4 d1 = __builtin_amdgcn_mfma_f32_16x16x32_fp8_fp8(Abc0[par][nt], az[0], zero, 0, 0, 0);
      d1       = __builtin_amdgcn_mfma_f32_16x16x32_fp8_fp8(Abc1[par][nt], az[1], d1,   0, 0, 0);
      f32x4 d2 = __builtin_amdgcn_mfma_f32_16x16x32_fp8_fp8(Abw0[par][nt], az[0], zero, 0, 0, 0);
      d2       = __builtin_amdgcn_mfma_f32_16x16x32_fp8_fp8(Abw1[par][nt], az[1], d2,   0, 0, 0);
      d1a[nt] = d1;
      d2a[nt] = d2;
    }

    // ---- prefetch next chunk: elementwise below covers the L2 latency ----
    LOADB(par ^ 1, cbase + ((it + 1) & 15) * 32);

    // ---- elementwise (6 ops/elem): p = exp2(clamped), dl accum, pack ----
    uint u0, u1;
#pragma unroll
    for (int nt = 0; nt < 2; ++nt) {
      float pv[4];
#pragma unroll
      for (int i = 0; i < 4; ++i) {
        float tt = fmaf(d1a[nt][i], 2.f, nzz);        // 2 d1 - zz
        float e  = fmaf(ilv[nt][i], tt, a0v[nt][i]);  // il2*(2d1-zz) - cc*il2
        e = fminf(e, 0.f);
        float p;
        asm("v_exp_f32 %0, %1" : "=v"(p) : "v"(e));   // exp2
        float g = fmaf(d2a[nt][i], ivv[nt][i], nqv[nt][i]); // inv*d2 - inv*q
        dl = fmaf(p, g, dl);
        pv[i] = p;
      }
      uint uv = pk4_fp8(pv[0], pv[1], pv[2], pv[3]);
      if (nt == 0) u0 = uv; else u1 = uv;
    }

    // ---- in-wave transpose: phi (own-row layout) -> GEMM2 A-fragment ----
    int  sl = lrow + ((lane & 16) << 1);   // lrow + 32*(t&1)
    bool hh = lane >= 32;                  // nt = t>>1
    uint l0a = __shfl(u0, sl),      l1a = __shfl(u1, sl);
    uint h0a = __shfl(u0, sl + 16), h1a = __shfl(u1, sl + 16);
    uint lo0 = hh ? l1a : l0a,      hi0 = hh ? h1a : h0a;
    long ap0 = (long)(((ulong_)hi0 << 32) | lo0);

    // ---- GEMM2: dz += phi @ Wz ----
    __builtin_amdgcn_s_setprio(1);
#pragma unroll
    for (int nt = 0; nt < 4; ++nt)
      acc[nt] = __builtin_amdgcn_mfma_f32_16x16x32_fp8_fp8(ap0, Abb[par][nt], acc[nt], 0, 0, 0);
    __builtin_amdgcn_s_setprio(0);
  }
#undef LOADB

  // ---- dl partial: sum over the 4 quads holding the same row ----
  {
    float v = dl;
    v += __shfl_xor(v, 16);
    v += __shfl_xor(v, 32);
    if (quad == 0) dlr[ws][lrow] = v;
  }

  // ---- dz combine across the 4 c-split waves ----
  for (int s = 0; s < 4; ++s) {
    __syncthreads();
    if (ws == s) {
#pragma unroll
      for (int nt = 0; nt < 4; ++nt)
#pragma unroll
        for (int i = 0; i < 4; ++i) {
          int r = quad * 4 + i;
          int d = nt * 16 + lrow;
          if (s == 0) eps[r * 68 + d] = acc[nt][i];
          else        eps[r * 68 + d] += acc[nt][i];
        }
    }
  }
  __syncthreads();

  // ---- outputs ----
  {
    int r = tid >> 4, d0 = (tid & 15) * 4;  // 256 thr x 4 floats = 16x64
    float4 e0 = *(const float4*)&eps[r * 68 + d0];
    float4 bv0 = *(const float4*)&bias[d0];
    float4 o0;
    o0.x = e0.x + bv0.x; o0.y = e0.y + bv0.y; o0.z = e0.z + bv0.z; o0.w = e0.w + bv0.w;
    *(float4*)&out[(size_t)(b0 + r) * DD + d0] = o0;
  }
  if (tid < 16) {
    float s = dlr[0][tid] + dlr[1][tid] + dlr[2][tid] + dlr[3][tid];
    out[(size_t)BB * DD + b0 + tid] = 2.f * s;
  }
}

// ---------------------------------------------------------------------------
extern "C" void kernel_launch(void* const* d_in, const int* in_sizes, int n_in,
                              void* d_out, int out_size, void* d_ws, size_t ws_size,
                              hipStream_t stream)
{
  const float* t   = (const float*)d_in[0];
  const float* z   = (const float*)d_in[1];
  // d_in[2] = logp_z (unused)
  const float* cz  = (const float*)d_in[3];
  const float* lsz = (const float*)d_in[4];
  const float* ct  = (const float*)d_in[5];
  const float* lst = (const float*)d_in[6];
  const float* W   = (const float*)d_in[7];
  float* out = (float*)d_out;
  float* ws  = (float*)d_ws;

  float*  bias = ws + BIAS_OFF;
  float*  il2a = ws + IL2_OFF;
  float*  a0a  = ws + A0_OFF;
  float*  niqa = ws + NIQ_OFF;
  float*  inva = ws + INV_OFF;
  uchar*  cz8a = (uchar*)(ws + CZ8A_OFF);
  uchar*  cz8b = (uchar*)(ws + CZ8B_OFF);
  uchar*  wz8a = (uchar*)(ws + WZ8A_OFF);
  uchar*  wz8b = (uchar*)(ws + WZ8B_OFF);
  uchar*  wzbp8 = (uchar*)(ws + WZBP_OFF);
  float*  part = ws + PART_OFF;

  k_wt1<<<dim3(9, 64, 4), 256, 0, stream>>>(t, ct, lst, W, part);
  k_prep2<<<dim3(256), 256, 0, stream>>>(part, cz, lsz, bias,
                                         il2a, a0a, niqa, inva,
                                         cz8a, cz8b, wz8a, wz8b, wzbp8);
  k_fused<<<dim3(BB / 16), 256, 0, stream>>>(z, cz8a, cz8b,
                                             wz8a, wz8b, wzbp8,
                                             il2a, a0a, niqa, inva, bias, out);
}

// Round 10
// 143.171 us; speedup vs baseline: 1.0946x; 1.0946x over previous
//
#include <hip/hip_runtime.h>
#include <math.h>

typedef unsigned int uint;
typedef unsigned short ushort;
typedef unsigned char uchar;
typedef unsigned long ulong_;
typedef __attribute__((ext_vector_type(4))) float f32x4;

// Problem constants
#define BB  16384
#define DD  64
#define NT_ 128
#define NZ_ 2048
#define NJ_ 2049   // NZ+1

// workspace layout (float offsets) — all regions disjoint (R6 lesson: verify
// end offsets; wzbp8 is 131072 BYTES = 32768 floats).
#define BIAS_OFF 0         // fp32 [64]                        -> end 64
#define IL2_OFF  64        // il2[c] = exp(-2 lsz)*log2e [2048]  -> end 2112
#define A0_OFF   2112      // a0[c]  = -cc * il2          [2048] -> end 4160
#define NIQ_OFF  4160      // niq[c] = -inv * q           [2048] -> end 6208
#define INV_OFF  6208      // inv[c] = exp(-2 lsz)        [2048] -> end 8256
#define CZ8A_OFF 8256      // fp8 cz k0 [NZ][32] = 16384 floats  -> end 24640
#define CZ8B_OFF 24640     // fp8 cz k1                          -> end 41024
#define WZ8A_OFF 41024     // fp8 WzT k0                         -> end 57408
#define WZ8B_OFF 57408     // fp8 WzT k1                         -> end 73792
#define WZBP_OFF 73792     // fp8 Wz packed [64][64][32]B = 32768 floats -> end 106560
#define PART_OFF 106560    // fp32 partials [4][64][NJ_] = 524544 -> end 631104
// end 631104 floats ~= 2.52 MB

// ---------------- fp8 e4m3 (OCP) conversion helpers ----------------
#if __has_builtin(__builtin_amdgcn_cvt_pk_fp8_f32)
__device__ __forceinline__ uint pk4_fp8(float a, float b, float c, float d) {
  int v = __builtin_amdgcn_cvt_pk_fp8_f32(a, b, 0, false);
  v = __builtin_amdgcn_cvt_pk_fp8_f32(c, d, v, true);
  return (uint)v;
}
__device__ __forceinline__ uchar f8_1(float x) {
  return (uchar)(__builtin_amdgcn_cvt_pk_fp8_f32(x, x, 0, false) & 0xFF);
}
#else
__device__ __forceinline__ uint sw_f8(float x) {
  uint u = __float_as_uint(x);
  uint s = (u >> 24) & 0x80u;
  float ax = __uint_as_float(u & 0x7FFFFFFFu);
  if (!(ax >= 0.015625f)) return s;          // flush tiny / NaN -> signed zero
  if (ax >= 448.f) return s | 0x7Eu;
  uint q = __float_as_uint(ax);
  q += 0x7FFFFu + ((q >> 20) & 1u);          // RNE at mantissa bit 20
  uint e = (q >> 23) - 120u;                 // rebias (127 -> 7)
  return s | ((e & 0xFu) << 3) | ((q >> 20) & 7u);
}
__device__ __forceinline__ uchar f8_1(float x) { return (uchar)sw_f8(x); }
__device__ __forceinline__ uint pk4_fp8(float a, float b, float c, float d) {
  return sw_f8(a) | (sw_f8(b) << 8) | (sw_f8(c) << 16) | (sw_f8(d) << 24);
}
#endif

// async global -> LDS copy, 16 B per lane: lane l fetches g (per-lane addr)
// and HW writes lds_base + l*16 (wave-uniform base).
__device__ __forceinline__ void stage16(const void* g, void* l) {
  __builtin_amdgcn_global_load_lds(
      (const __attribute__((address_space(1))) uint*)g,
      (__attribute__((address_space(3))) uint*)l, 16, 0, 0);
}

// ---------------------------------------------------------------------------
// Kernel 1 (stage 1): split-K partial sums of W_t = einsum('dij,i->dj').
// 2304 blocks (9/CU, 32 waves/CU) -> latency-tolerant W read (67 MB, BW-bound,
// ~5.2 TB/s, near the 10.6us floor). R2: fewer waves/CU collapses to 330 GB/s.
__global__ __launch_bounds__(256) void k_wt1(
    const float* __restrict__ t, const float* __restrict__ ct,
    const float* __restrict__ lst, const float* __restrict__ W,
    float* __restrict__ part)   // [4][64][NJ_]
{
  __shared__ float ph[32];
  int tx = threadIdx.x;
  int d  = blockIdx.y;
  int ic = blockIdx.z;
  if (tx < 32) {
    int i = ic * 32 + tx;
    float r = fabsf(t[0] - ct[i]) * __expf(-lst[i]);
    ph[tx] = __expf(-r * r);
  }
  __syncthreads();
  int j = blockIdx.x * 256 + tx;
  if (j >= NJ_) return;
  const float* Wp = W + (size_t)d * NT_ * NJ_ + (size_t)(ic * 32) * NJ_ + j;
  float acc = 0.f;
#pragma unroll
  for (int k = 0; k < 32; ++k) acc += Wp[(size_t)k * NJ_] * ph[k];
  part[((size_t)ic * 64 + d) * NJ_ + j] = acc;
}

// ---------------------------------------------------------------------------
// Kernel 2 (stage 2): 256 blocks x 256 thr, 8 centres/block.
// Emits PLANAR per-centre constants {il2, a0, niq, inv}.
__global__ __launch_bounds__(256) void k_prep2(
    const float* __restrict__ part, const float* __restrict__ cz,
    const float* __restrict__ lsz,
    float* __restrict__ bias,
    float* __restrict__ il2a, float* __restrict__ a0a, float* __restrict__ niqa,
    float* __restrict__ inva,
    uchar* __restrict__ cz8a, uchar* __restrict__ cz8b,
    uchar* __restrict__ wz8a, uchar* __restrict__ wz8b,
    uchar* __restrict__ wzbp8)
{
  __shared__ float wt[64][9];   // [d][c_local]
  int tid = threadIdx.x;
  int cb0 = blockIdx.x * 8;
#pragma unroll
  for (int h = 0; h < 2; ++h) {
    int f = h * 256 + tid;      // 512 = 64 d x 8 c
    int d = f >> 3, c = f & 7;
    size_t idx = (size_t)d * NJ_ + cb0 + c;
    float s = part[idx] + part[(size_t)64 * NJ_ + idx]
            + part[(size_t)128 * NJ_ + idx] + part[(size_t)192 * NJ_ + idx];
    wt[d][c] = s;
    int cg = cb0 + c;
    wzbp8[((size_t)(cg >> 5) * 64 + d) * 32 + (cg & 31)] = f8_1(s);
  }
  if (blockIdx.x == 0 && tid < 64) {
    size_t idx = (size_t)tid * NJ_ + 2048;
    bias[tid] = part[idx] + part[(size_t)64 * NJ_ + idx]
              + part[(size_t)128 * NJ_ + idx] + part[(size_t)192 * NJ_ + idx];
  }
  __syncthreads();
  int cl = tid >> 5;            // centre within block 0..7
  int k  = tid & 31;            // 0..31
  int c  = cb0 + cl;
  float cv0 = cz[(size_t)c * DD + k];
  float cv1 = cz[(size_t)c * DD + 32 + k];
  cz8a[(size_t)c * 32 + k] = f8_1(cv0);
  cz8b[(size_t)c * 32 + k] = f8_1(cv1);
  float w0 = wt[k][cl], w1 = wt[32 + k][cl];
  wz8a[(size_t)c * 32 + k] = f8_1(w0);
  wz8b[(size_t)c * 32 + k] = f8_1(w1);
  float ca = cv0 * cv0 + cv1 * cv1;
  float qa = w0 * cv0 + w1 * cv1;
  qa += __shfl_xor(qa, 1);  ca += __shfl_xor(ca, 1);
  qa += __shfl_xor(qa, 2);  ca += __shfl_xor(ca, 2);
  qa += __shfl_xor(qa, 4);  ca += __shfl_xor(ca, 4);
  qa += __shfl_xor(qa, 8);  ca += __shfl_xor(ca, 8);
  qa += __shfl_xor(qa, 16); ca += __shfl_xor(ca, 16);
  if (k == 0) {
    float inv = __expf(-2.f * lsz[c]);
    float il2 = inv * 1.44269504f;     // inv * log2e
    il2a[c] = il2;
    a0a[c]  = -ca * il2;               // -cc * il2
    niqa[c] = -inv * qa;               // -inv * q
    inva[c] = inv;
  }
}

// ---------------------------------------------------------------------------
// Main fused MFMA kernel — R10: LDS-staged async pipeline.
// Cross-round evidence (R4/R8/R9): register-based prefetch is defeated by the
// allocator at every shape except R7's exact one (spill at 64 VGPR forced, or
// dbuf rematerialized at 84). Fix: prefetch via global_load_lds into per-wave
// PRIVATE double-buffered LDS tiles — fire-and-forget DMA the allocator can't
// touch, counted vmcnt(7) (never 0 in-loop), no barriers (no cross-wave LDS
// sharing until the epilogue). All loop VMEM is stage-only, so the compiler
// has no reason to drain vmcnt before elementwise (the R9 const-load trap).
// Per-wave tile (7168 B x 2 bufs): [cz8a 1K][cz8b 1K][wz8a 1K][wz8b 1K]
// [wzbp 2K][consts 1K: il2|a0|niq|inv x 128B, lanes 32-63 write a dup].
// BM=32 grid 512 (best table amortization; BM=16 doubled load instrs, R8/R9).
__global__ __launch_bounds__(256, 2) void k_fused(
    const float* __restrict__ z,
    const uchar* __restrict__ cz8a, const uchar* __restrict__ cz8b,
    const uchar* __restrict__ wz8a, const uchar* __restrict__ wz8b,
    const uchar* __restrict__ wzbp8,
    const float* __restrict__ il2a, const float* __restrict__ a0a,
    const float* __restrict__ niqa, const float* __restrict__ inva,
    const float* __restrict__ bias, float* __restrict__ out)
{
  // stage buffers during loop; eps combine scratch reuses the same LDS after
  // the final vmcnt(0) drain + epilogue barriers. dlr is separate (written
  // pre-barrier).
  __shared__ __align__(16) uchar smem[4 * 2 * 7168];   // 56 KiB
  __shared__ float dlr[4][32];
  float* eps = (float*)smem;                            // 32*68*4 = 8704 B

  int tid  = threadIdx.x;
  int ws   = tid >> 6;           // wave = c-split group 0..3
  int lane = tid & 63;
  int lrow = lane & 15, quad = lane >> 4;
  int b0 = blockIdx.x * 32;

  // ---- prologue: read fp32 z rows, pack fp8 frags + own-row norms ----
  long az[2][2];
  float nzz[2];
#pragma unroll
  for (int mt = 0; mt < 2; ++mt) {
    const float* zr = z + (size_t)(b0 + mt * 16 + lrow) * DD + quad * 8;
    float4 v0 = *(const float4*)zr;
    float4 v1 = *(const float4*)(zr + 4);
    float4 v2 = *(const float4*)(zr + 32);
    float4 v3 = *(const float4*)(zr + 36);
    uint l0 = pk4_fp8(v0.x, v0.y, v0.z, v0.w);
    uint l1 = pk4_fp8(v1.x, v1.y, v1.z, v1.w);
    uint h0 = pk4_fp8(v2.x, v2.y, v2.z, v2.w);
    uint h1 = pk4_fp8(v3.x, v3.y, v3.z, v3.w);
    az[mt][0] = (long)(((ulong_)l1 << 32) | l0);
    az[mt][1] = (long)(((ulong_)h1 << 32) | h0);
    float ss = v0.x * v0.x + v0.y * v0.y + v0.z * v0.z + v0.w * v0.w
             + v1.x * v1.x + v1.y * v1.y + v1.z * v1.z + v1.w * v1.w
             + v2.x * v2.x + v2.y * v2.y + v2.z * v2.z + v2.w * v2.w
             + v3.x * v3.x + v3.y * v3.y + v3.z * v3.z + v3.w * v3.w;
    ss += __shfl_xor(ss, 16);
    ss += __shfl_xor(ss, 32);
    nzz[mt] = -ss;               // own row's -|z|^2
  }

  // per-lane base for the 4-way consts gather (il2|a0|niq|inv by lane>>3)
  int asel = (lane >> 3) & 3;
  const float* myA = asel == 0 ? il2a : asel == 1 ? a0a : asel == 2 ? niqa : inva;
  const uchar* myAb = (const uchar*)myA + (size_t)(lane & 7) * 16;

  f32x4 acc[2][4];
#pragma unroll
  for (int mt = 0; mt < 2; ++mt)
#pragma unroll
    for (int nt = 0; nt < 4; ++nt) acc[mt][nt] = (f32x4){0.f, 0.f, 0.f, 0.f};
  float dl[2] = {0.f, 0.f};

  const f32x4 zero = (f32x4){0.f, 0.f, 0.f, 0.f};
  int cbase = ws * 512;
  uchar* wlds = smem + (size_t)ws * 14336;   // this wave's 2 stage buffers

// 7 async stages for chunk C0 into buffer B (wave-private).
#define STAGE(B, C0)                                                           \
  do {                                                                         \
    uchar* lb_ = wlds + (B) * 7168;                                            \
    size_t go_ = (size_t)(C0) * 32 + (size_t)lane * 16;                        \
    stage16(cz8a + go_, lb_);                                                  \
    stage16(cz8b + go_, lb_ + 1024);                                           \
    stage16(wz8a + go_, lb_ + 2048);                                           \
    stage16(wz8b + go_, lb_ + 3072);                                           \
    const uchar* wb_ = wzbp8 + ((size_t)((C0) >> 5)) * 2048 + (size_t)lane * 16; \
    stage16(wb_, lb_ + 4096);                                                  \
    stage16(wb_ + 1024, lb_ + 5120);                                           \
    stage16(myAb + (size_t)(C0) * 4, lb_ + 6144);                              \
  } while (0)

  STAGE(0, cbase);
#pragma unroll 2
  for (int it = 0; it < 16; ++it) {
    int buf = it & 1;
    // issue next chunk's stages (wraps on last iter -> harmless, drained below)
    STAGE(buf ^ 1, cbase + ((it + 1) & 15) * 32);
    // wait current buffer's 7 (issued last iter); next 7 stay in flight
    asm volatile("s_waitcnt vmcnt(7)" ::: "memory");
    __builtin_amdgcn_sched_barrier(0);

    const uchar* tb = wlds + buf * 7168;
    long Abc0[2], Abc1[2], Abw0[2], Abw1[2], Abb[4];
    float4 ilv[2], a0v[2], nqv[2], ivv[2];
#pragma unroll
    for (int nt = 0; nt < 2; ++nt) {
      int off = (nt * 16 + lrow) * 32 + quad * 8;
      Abc0[nt] = *(const long*)(tb + off);
      Abc1[nt] = *(const long*)(tb + 1024 + off);
      Abw0[nt] = *(const long*)(tb + 2048 + off);
      Abw1[nt] = *(const long*)(tb + 3072 + off);
      int coff = (nt * 16 + quad * 4) * 4;
      ilv[nt] = *(const float4*)(tb + 6144 + coff);
      a0v[nt] = *(const float4*)(tb + 6144 + 128 + coff);
      nqv[nt] = *(const float4*)(tb + 6144 + 256 + coff);
      ivv[nt] = *(const float4*)(tb + 6144 + 384 + coff);
    }
#pragma unroll
    for (int nt = 0; nt < 4; ++nt)
      Abb[nt] = *(const long*)(tb + 4096 + (nt * 16 + lrow) * 32 + quad * 8);

    // ---- GEMM1 (swapped): thread owns row lrow, c = c0+nt*16+quad*4+i ----
    f32x4 d1a[2][2], d2a[2][2];
#pragma unroll
    for (int nt = 0; nt < 2; ++nt)
#pragma unroll
      for (int mt = 0; mt < 2; ++mt) {
        f32x4 d1 = __builtin_amdgcn_mfma_f32_16x16x32_fp8_fp8(Abc0[nt], az[mt][0], zero, 0, 0, 0);
        d1       = __builtin_amdgcn_mfma_f32_16x16x32_fp8_fp8(Abc1[nt], az[mt][1], d1,   0, 0, 0);
        f32x4 d2 = __builtin_amdgcn_mfma_f32_16x16x32_fp8_fp8(Abw0[nt], az[mt][0], zero, 0, 0, 0);
        d2       = __builtin_amdgcn_mfma_f32_16x16x32_fp8_fp8(Abw1[nt], az[mt][1], d2,   0, 0, 0);
        d1a[nt][mt] = d1;
        d2a[nt][mt] = d2;
      }

    // ---- elementwise (6 ops/elem): p = exp2(clamped), dl accum, pack ----
    uint u00, u01, u10, u11;
#pragma unroll
    for (int mt = 0; mt < 2; ++mt)
#pragma unroll
      for (int nt = 0; nt < 2; ++nt) {
        float pv[4];
#pragma unroll
        for (int i = 0; i < 4; ++i) {
          float tt = fmaf(d1a[nt][mt][i], 2.f, nzz[mt]);   // 2 d1 - zz
          float e  = fmaf(ilv[nt][i], tt, a0v[nt][i]);     // il2*(2d1-zz-cc)
          e = fminf(e, 0.f);
          float p;
          asm("v_exp_f32 %0, %1" : "=v"(p) : "v"(e));      // exp2
          float g = fmaf(d2a[nt][mt][i], ivv[nt][i], nqv[nt][i]); // inv*(d2-q)
          dl[mt] = fmaf(p, g, dl[mt]);
          pv[i] = p;
        }
        uint uv = pk4_fp8(pv[0], pv[1], pv[2], pv[3]);
        if (mt == 0) { if (nt == 0) u00 = uv; else u01 = uv; }
        else         { if (nt == 0) u10 = uv; else u11 = uv; }
      }

    // ---- in-wave transpose: phi (own-row layout) -> GEMM2 A-fragments ----
    int  sl = lrow + ((lane & 16) << 1);   // lrow + 32*(t&1)
    bool hh = lane >= 32;                  // nt = t>>1
    uint l0a = __shfl(u00, sl),      l1a = __shfl(u01, sl);
    uint h0a = __shfl(u00, sl + 16), h1a = __shfl(u01, sl + 16);
    uint lo0 = hh ? l1a : l0a,       hi0 = hh ? h1a : h0a;
    long ap0 = (long)(((ulong_)hi0 << 32) | lo0);
    uint l0b = __shfl(u10, sl),      l1b = __shfl(u11, sl);
    uint h0b = __shfl(u10, sl + 16), h1b = __shfl(u11, sl + 16);
    uint lo1 = hh ? l1b : l0b,       hi1 = hh ? h1b : h0b;
    long ap1 = (long)(((ulong_)hi1 << 32) | lo1);

    // ---- GEMM2: dz += phi @ Wz ----
    __builtin_amdgcn_s_setprio(1);
#pragma unroll
    for (int nt = 0; nt < 4; ++nt) {
      acc[0][nt] = __builtin_amdgcn_mfma_f32_16x16x32_fp8_fp8(ap0, Abb[nt], acc[0][nt], 0, 0, 0);
      acc[1][nt] = __builtin_amdgcn_mfma_f32_16x16x32_fp8_fp8(ap1, Abb[nt], acc[1][nt], 0, 0, 0);
    }
    __builtin_amdgcn_s_setprio(0);
  }
#undef STAGE
  // drain the wrap-around stages before the LDS is reused for eps (and before
  // block retire — stale DMA landing in a successor block's LDS is a race)
  asm volatile("s_waitcnt vmcnt(0)" ::: "memory");

  // ---- dl partials: sum over the 4 quads holding the same row ----
#pragma unroll
  for (int mt = 0; mt < 2; ++mt) {
    float v = dl[mt];
    v += __shfl_xor(v, 16);
    v += __shfl_xor(v, 32);
    if (quad == 0) dlr[ws][mt * 16 + lrow] = v;
  }

  // ---- dz combine across the 4 c-split waves (eps reuses stage LDS) ----
  for (int s = 0; s < 4; ++s) {
    __syncthreads();
    if (ws == s) {
#pragma unroll
      for (int mt = 0; mt < 2; ++mt)
#pragma unroll
        for (int nt = 0; nt < 4; ++nt)
#pragma unroll
          for (int i = 0; i < 4; ++i) {
            int r = mt * 16 + quad * 4 + i;
            int d = nt * 16 + lrow;
            if (s == 0) eps[r * 68 + d] = acc[mt][nt][i];
            else        eps[r * 68 + d] += acc[mt][nt][i];
          }
    }
  }
  __syncthreads();

  // ---- outputs ----
  {
    int r = tid >> 3, d0 = (tid & 7) * 8;   // 256 thr x 8 floats = 32x64
    float4 e0 = *(const float4*)&eps[r * 68 + d0];
    float4 e1 = *(const float4*)&eps[r * 68 + d0 + 4];
    float4 bv0 = *(const float4*)&bias[d0];
    float4 bv1 = *(const float4*)&bias[d0 + 4];
    float4 o0, o1;
    o0.x = e0.x + bv0.x; o0.y = e0.y + bv0.y; o0.z = e0.z + bv0.z; o0.w = e0.w + bv0.w;
    o1.x = e1.x + bv1.x; o1.y = e1.y + bv1.y; o1.z = e1.z + bv1.z; o1.w = e1.w + bv1.w;
    *(float4*)&out[(size_t)(b0 + r) * DD + d0]     = o0;
    *(float4*)&out[(size_t)(b0 + r) * DD + d0 + 4] = o1;
  }
  if (tid < 32) {
    float s = dlr[0][tid] + dlr[1][tid] + dlr[2][tid] + dlr[3][tid];
    out[(size_t)BB * DD + b0 + tid] = 2.f * s;
  }
}

// ---------------------------------------------------------------------------
extern "C" void kernel_launch(void* const* d_in, const int* in_sizes, int n_in,
                              void* d_out, int out_size, void* d_ws, size_t ws_size,
                              hipStream_t stream)
{
  const float* t   = (const float*)d_in[0];
  const float* z   = (const float*)d_in[1];
  // d_in[2] = logp_z (unused)
  const float* cz  = (const float*)d_in[3];
  const float* lsz = (const float*)d_in[4];
  const float* ct  = (const float*)d_in[5];
  const float* lst = (const float*)d_in[6];
  const float* W   = (const float*)d_in[7];
  float* out = (float*)d_out;
  float* ws  = (float*)d_ws;

  float*  bias = ws + BIAS_OFF;
  float*  il2a = ws + IL2_OFF;
  float*  a0a  = ws + A0_OFF;
  float*  niqa = ws + NIQ_OFF;
  float*  inva = ws + INV_OFF;
  uchar*  cz8a = (uchar*)(ws + CZ8A_OFF);
  uchar*  cz8b = (uchar*)(ws + CZ8B_OFF);
  uchar*  wz8a = (uchar*)(ws + WZ8A_OFF);
  uchar*  wz8b = (uchar*)(ws + WZ8B_OFF);
  uchar*  wzbp8 = (uchar*)(ws + WZBP_OFF);
  float*  part = ws + PART_OFF;

  k_wt1<<<dim3(9, 64, 4), 256, 0, stream>>>(t, ct, lst, W, part);
  k_prep2<<<dim3(256), 256, 0, stream>>>(part, cz, lsz, bias,
                                         il2a, a0a, niqa, inva,
                                         cz8a, cz8b, wz8a, wz8b, wzbp8);
  k_fused<<<dim3(BB / 32), 256, 0, stream>>>(z, cz8a, cz8b,
                                             wz8a, wz8b, wzbp8,
                                             il2a, a0a, niqa, inva, bias, out);
}

// Round 11
// 136.407 us; speedup vs baseline: 1.1489x; 1.0496x over previous
//
#include <hip/hip_runtime.h>
#include <math.h>

typedef unsigned int uint;
typedef unsigned short ushort;
typedef unsigned char uchar;
typedef unsigned long ulong_;
typedef __attribute__((ext_vector_type(4))) float f32x4;
typedef __attribute__((ext_vector_type(2))) unsigned long ulongx2;

// Problem constants
#define BB  16384
#define DD  64
#define NT_ 128
#define NZ_ 2048
#define NJ_ 2049   // NZ+1

// workspace layout (float offsets) — all regions disjoint (R6 lesson: verify
// end offsets; byte-sized tables: floats = bytes/4).
#define BIAS_OFF 0         // fp32 [64]                         -> end 64
#define IL2_OFF  64        // il2[c] = exp(-2 lsz)*log2e [2048]   -> end 2112
#define A0_OFF   2112      // a0[c]  = -cc * il2          [2048]  -> end 4160
#define NIQ_OFF  4160      // niq[c] = -inv * q           [2048]  -> end 6208
#define CZP_OFF  6208      // fp8 cz paired [NZ][64]B = 32768 fl  -> end 38976
#define WZP_OFF  38976     // fp8 inv*Wz paired [NZ][64]B = 32768 -> end 71744
#define WZBP_OFF 71744     // fp8 Wz packed [64][64][32]B = 32768 -> end 104512
#define PART_OFF 104512    // fp32 partials [4][64][NJ_] = 524544 -> end 629056
// end 629056 floats ~= 2.52 MB

// ---------------- fp8 e4m3 (OCP) conversion helpers ----------------
#if __has_builtin(__builtin_amdgcn_cvt_pk_fp8_f32)
__device__ __forceinline__ uint pk4_fp8(float a, float b, float c, float d) {
  int v = __builtin_amdgcn_cvt_pk_fp8_f32(a, b, 0, false);
  v = __builtin_amdgcn_cvt_pk_fp8_f32(c, d, v, true);
  return (uint)v;
}
__device__ __forceinline__ uchar f8_1(float x) {
  return (uchar)(__builtin_amdgcn_cvt_pk_fp8_f32(x, x, 0, false) & 0xFF);
}
#else
__device__ __forceinline__ uint sw_f8(float x) {
  uint u = __float_as_uint(x);
  uint s = (u >> 24) & 0x80u;
  float ax = __uint_as_float(u & 0x7FFFFFFFu);
  if (!(ax >= 0.015625f)) return s;          // flush tiny / NaN -> signed zero
  if (ax >= 448.f) return s | 0x7Eu;
  uint q = __float_as_uint(ax);
  q += 0x7FFFFu + ((q >> 20) & 1u);          // RNE at mantissa bit 20
  uint e = (q >> 23) - 120u;                 // rebias (127 -> 7)
  return s | ((e & 0xFu) << 3) | ((q >> 20) & 7u);
}
__device__ __forceinline__ uchar f8_1(float x) { return (uchar)sw_f8(x); }
__device__ __forceinline__ uint pk4_fp8(float a, float b, float c, float d) {
  return sw_f8(a) | (sw_f8(b) << 8) | (sw_f8(c) << 16) | (sw_f8(d) << 24);
}
#endif

// ---------------------------------------------------------------------------
// Kernel 1 (stage 1): split-K partial sums of W_t = einsum('dij,i->dj').
// 2304 blocks (9/CU, 32 waves/CU) -> latency-tolerant W read (67 MB, BW-bound,
// ~5.2 TB/s, near the 10.6us floor). R2: fewer waves/CU collapses to 330 GB/s.
__global__ __launch_bounds__(256) void k_wt1(
    const float* __restrict__ t, const float* __restrict__ ct,
    const float* __restrict__ lst, const float* __restrict__ W,
    float* __restrict__ part)   // [4][64][NJ_]
{
  __shared__ float ph[32];
  int tx = threadIdx.x;
  int d  = blockIdx.y;
  int ic = blockIdx.z;
  if (tx < 32) {
    int i = ic * 32 + tx;
    float r = fabsf(t[0] - ct[i]) * __expf(-lst[i]);
    ph[tx] = __expf(-r * r);
  }
  __syncthreads();
  int j = blockIdx.x * 256 + tx;
  if (j >= NJ_) return;
  const float* Wp = W + (size_t)d * NT_ * NJ_ + (size_t)(ic * 32) * NJ_ + j;
  float acc = 0.f;
#pragma unroll
  for (int k = 0; k < 32; ++k) acc += Wp[(size_t)k * NJ_] * ph[k];
  part[((size_t)ic * 64 + d) * NJ_ + j] = acc;
}

// ---------------------------------------------------------------------------
// Kernel 2 (stage 2): 256 blocks x 256 thr, 8 centres/block.
// R11: emits PAIRED k-half tables — czp[c][64]B = {cz k0 16B | cz k1 16B}
// repeated per 8-k group, so one dwordx4 in k_fused feeds BOTH k-half MFMA
// fragments (was two b64 loads from separate arrays). wzp additionally
// pre-scaled by inv so the hot loop's g-term is a plain add (inv==1 when
// log_sigmas_z==0 -> bit-identical quantization to the unscaled table here).
__global__ __launch_bounds__(256) void k_prep2(
    const float* __restrict__ part, const float* __restrict__ cz,
    const float* __restrict__ lsz,
    float* __restrict__ bias,
    float* __restrict__ il2a, float* __restrict__ a0a, float* __restrict__ niqa,
    uchar* __restrict__ czp, uchar* __restrict__ wzp,
    uchar* __restrict__ wzbp8)
{
  __shared__ float wt[64][9];   // [d][c_local]
  int tid = threadIdx.x;
  int cb0 = blockIdx.x * 8;
#pragma unroll
  for (int h = 0; h < 2; ++h) {
    int f = h * 256 + tid;      // 512 = 64 d x 8 c
    int d = f >> 3, c = f & 7;
    size_t idx = (size_t)d * NJ_ + cb0 + c;
    float s = part[idx] + part[(size_t)64 * NJ_ + idx]
            + part[(size_t)128 * NJ_ + idx] + part[(size_t)192 * NJ_ + idx];
    wt[d][c] = s;
    int cg = cb0 + c;
    wzbp8[((size_t)(cg >> 5) * 64 + d) * 32 + (cg & 31)] = f8_1(s);
  }
  if (blockIdx.x == 0 && tid < 64) {
    size_t idx = (size_t)tid * NJ_ + 2048;
    bias[tid] = part[idx] + part[(size_t)64 * NJ_ + idx]
              + part[(size_t)128 * NJ_ + idx] + part[(size_t)192 * NJ_ + idx];
  }
  __syncthreads();
  int cl = tid >> 5;            // centre within block 0..7
  int k  = tid & 31;            // 0..31
  int c  = cb0 + cl;
  float inv = __expf(-2.f * lsz[c]);
  float cv0 = cz[(size_t)c * DD + k];
  float cv1 = cz[(size_t)c * DD + 32 + k];
  // paired layout: [c][ (k>>3)*16 + (k&7) ] = k0 half, +8 = k1 half
  size_t pbase = (size_t)c * 64 + ((k >> 3) << 4) + (k & 7);
  czp[pbase]     = f8_1(cv0);
  czp[pbase + 8] = f8_1(cv1);
  float w0 = wt[k][cl], w1 = wt[32 + k][cl];
  wzp[pbase]     = f8_1(w0 * inv);
  wzp[pbase + 8] = f8_1(w1 * inv);
  float ca = cv0 * cv0 + cv1 * cv1;
  float qa = w0 * cv0 + w1 * cv1;   // q uses exact (unscaled) Wz
  qa += __shfl_xor(qa, 1);  ca += __shfl_xor(ca, 1);
  qa += __shfl_xor(qa, 2);  ca += __shfl_xor(ca, 2);
  qa += __shfl_xor(qa, 4);  ca += __shfl_xor(ca, 4);
  qa += __shfl_xor(qa, 8);  ca += __shfl_xor(ca, 8);
  qa += __shfl_xor(qa, 16); ca += __shfl_xor(ca, 16);
  if (k == 0) {
    float il2 = inv * 1.44269504f;     // inv * log2e
    il2a[c] = il2;
    a0a[c]  = -ca * il2;               // -cc * il2
    niqa[c] = -inv * qa;               // -inv * q
  }
}

// ---------------------------------------------------------------------------
// Main fused MFMA kernel — R11: R7 base (best measured, 137.55 total) with
// three additive micro-trims. Structure is UNCHANGED from R7 (BM=32, grid 512,
// (256,2), register double-buffer — the only regime where the allocator keeps
// the prefetch live; R4/R8/R9/R10 all regressed when this was perturbed):
//  1. paired tables: one dwordx4 -> both k-half fragments (VMEM 18->14/chunk)
//  2. wzp pre-scaled by inv: g = d2' + niq (v_add, no fma w/ ln2 constant)
//  3. 2-fma exponent path: e = il2*(2 d1 + nzz) + a0
// Swapped-operand GEMM1 + in-wave shuffle transpose (R7): thread owns its
// z-row; phi -> GEMM2-A-frag is 8 shfl + 4 select, no phi LDS buffer.
__global__ __launch_bounds__(256, 2) void k_fused(
    const float* __restrict__ z,
    const uchar* __restrict__ czp, const uchar* __restrict__ wzp,
    const uchar* __restrict__ wzbp8,
    const float* __restrict__ il2a, const float* __restrict__ a0a,
    const float* __restrict__ niqa,
    const float* __restrict__ bias, float* __restrict__ out)
{
  __shared__ float eps[32 * 68];   // dz combine scratch (only LDS use)
  __shared__ float dlr[4][32];

  int tid  = threadIdx.x;
  int ws   = tid >> 6;           // wave = c-split group 0..3
  int lane = tid & 63;
  int lrow = lane & 15, quad = lane >> 4;
  int b0 = blockIdx.x * 32;

  // ---- prologue: read fp32 z rows, pack fp8 frags + own-row norms ----
  long az[2][2];
  float nzz[2];
#pragma unroll
  for (int mt = 0; mt < 2; ++mt) {
    const float* zr = z + (size_t)(b0 + mt * 16 + lrow) * DD + quad * 8;
    float4 v0 = *(const float4*)zr;
    float4 v1 = *(const float4*)(zr + 4);
    float4 v2 = *(const float4*)(zr + 32);
    float4 v3 = *(const float4*)(zr + 36);
    uint l0 = pk4_fp8(v0.x, v0.y, v0.z, v0.w);
    uint l1 = pk4_fp8(v1.x, v1.y, v1.z, v1.w);
    uint h0 = pk4_fp8(v2.x, v2.y, v2.z, v2.w);
    uint h1 = pk4_fp8(v3.x, v3.y, v3.z, v3.w);
    az[mt][0] = (long)(((ulong_)l1 << 32) | l0);
    az[mt][1] = (long)(((ulong_)h1 << 32) | h0);
    float ss = v0.x * v0.x + v0.y * v0.y + v0.z * v0.z + v0.w * v0.w
             + v1.x * v1.x + v1.y * v1.y + v1.z * v1.z + v1.w * v1.w
             + v2.x * v2.x + v2.y * v2.y + v2.z * v2.z + v2.w * v2.w
             + v3.x * v3.x + v3.y * v3.y + v3.z * v3.z + v3.w * v3.w;
    ss += __shfl_xor(ss, 16);    // combine the 4 quad partials -> full row sum
    ss += __shfl_xor(ss, 32);
    nzz[mt] = -ss;               // own row's -|z|^2
  }

  f32x4 acc[2][4];
#pragma unroll
  for (int mt = 0; mt < 2; ++mt)
#pragma unroll
    for (int nt = 0; nt < 4; ++nt) acc[mt][nt] = (f32x4){0.f, 0.f, 0.f, 0.f};
  float dl[2] = {0.f, 0.f};

  const f32x4 zero = (f32x4){0.f, 0.f, 0.f, 0.f};
  int cbase = ws * 512;

  // ---- register double-buffered prefetch state (fp8 frags only) ----
  long Abc0[2][2], Abc1[2][2], Abw0[2][2], Abw1[2][2], Abb[2][4];
#define LOADB(PAR, C0)                                                         \
  do {                                                                         \
    int c0_ = (C0);                                                            \
    _Pragma("unroll")                                                          \
    for (int nt = 0; nt < 2; ++nt) {                                           \
      int cg_ = c0_ + nt * 16 + lrow;                                          \
      size_t po_ = (size_t)cg_ * 64 + quad * 16;                               \
      ulongx2 va_ = *(const ulongx2*)(czp + po_);                              \
      ulongx2 vw_ = *(const ulongx2*)(wzp + po_);                              \
      Abc0[PAR][nt] = (long)va_.x;                                             \
      Abc1[PAR][nt] = (long)va_.y;                                             \
      Abw0[PAR][nt] = (long)vw_.x;                                             \
      Abw1[PAR][nt] = (long)vw_.y;                                             \
    }                                                                          \
    size_t cb_ = (size_t)(c0_ >> 5) * 64 * 32;                                 \
    _Pragma("unroll")                                                          \
    for (int nt = 0; nt < 4; ++nt)                                             \
      Abb[PAR][nt] =                                                           \
          *(const long*)(wzbp8 + cb_ + (size_t)(nt * 16 + lrow) * 32 + quad * 8); \
  } while (0)

  LOADB(0, cbase);
#pragma unroll 2
  for (int it = 0; it < 16; ++it) {
    int par = it & 1;
    int c0  = cbase + it * 32;

    // current-chunk planar constants; consumed after GEMM1 (latency covered)
    float4 ilv[2], a0v[2], nqv[2];
#pragma unroll
    for (int nt = 0; nt < 2; ++nt) {
      int cb = c0 + nt * 16 + quad * 4;
      ilv[nt] = *(const float4*)&il2a[cb];
      a0v[nt] = *(const float4*)&a0a[cb];
      nqv[nt] = *(const float4*)&niqa[cb];
    }

    // ---- GEMM1 (swapped): D[c_local][r_local]; thread owns row lrow ----
    f32x4 d1a[2][2], d2a[2][2];
#pragma unroll
    for (int nt = 0; nt < 2; ++nt)
#pragma unroll
      for (int mt = 0; mt < 2; ++mt) {
        f32x4 d1 = __builtin_amdgcn_mfma_f32_16x16x32_fp8_fp8(Abc0[par][nt], az[mt][0], zero, 0, 0, 0);
        d1       = __builtin_amdgcn_mfma_f32_16x16x32_fp8_fp8(Abc1[par][nt], az[mt][1], d1,   0, 0, 0);
        f32x4 d2 = __builtin_amdgcn_mfma_f32_16x16x32_fp8_fp8(Abw0[par][nt], az[mt][0], zero, 0, 0, 0);
        d2       = __builtin_amdgcn_mfma_f32_16x16x32_fp8_fp8(Abw1[par][nt], az[mt][1], d2,   0, 0, 0);
        d1a[nt][mt] = d1;
        d2a[nt][mt] = d2;
      }

    // ---- prefetch next chunk: elementwise below covers the L2 latency ----
    LOADB(par ^ 1, cbase + ((it + 1) & 15) * 32);

    // ---- elementwise (6 ops/elem): p = exp2(clamped), dl accum, pack ----
    // element (mt,nt,i): r = b0+mt*16+lrow, c = c0+nt*16+quad*4+i
    uint u00, u01, u10, u11;
#pragma unroll
    for (int mt = 0; mt < 2; ++mt)
#pragma unroll
      for (int nt = 0; nt < 2; ++nt) {
        float pv[4];
#pragma unroll
        for (int i = 0; i < 4; ++i) {
          float tt = fmaf(d1a[nt][mt][i], 2.f, nzz[mt]);   // 2 d1 - zz
          float e  = fmaf(ilv[nt][i], tt, a0v[nt][i]);     // il2*(2d1-zz-cc)
          e = fminf(e, 0.f);
          float p;
          asm("v_exp_f32 %0, %1" : "=v"(p) : "v"(e));      // exp2
          float g = d2a[nt][mt][i] + nqv[nt][i];           // inv*(z.Wz - q)
          dl[mt] = fmaf(p, g, dl[mt]);
          pv[i] = p;
        }
        uint uv = pk4_fp8(pv[0], pv[1], pv[2], pv[3]);
        if (mt == 0) { if (nt == 0) u00 = uv; else u01 = uv; }
        else         { if (nt == 0) u10 = uv; else u11 = uv; }
      }

    // ---- in-wave transpose: phi (own-row layout) -> GEMM2 A-fragments ----
    int  sl = lrow + ((lane & 16) << 1);   // lrow + 32*(t&1)
    bool hh = lane >= 32;                  // nt = t>>1
    uint l0a = __shfl(u00, sl),      l1a = __shfl(u01, sl);
    uint h0a = __shfl(u00, sl + 16), h1a = __shfl(u01, sl + 16);
    uint lo0 = hh ? l1a : l0a,       hi0 = hh ? h1a : h0a;
    long ap0 = (long)(((ulong_)hi0 << 32) | lo0);
    uint l0b = __shfl(u10, sl),      l1b = __shfl(u11, sl);
    uint h0b = __shfl(u10, sl + 16), h1b = __shfl(u11, sl + 16);
    uint lo1 = hh ? l1b : l0b,       hi1 = hh ? h1b : h0b;
    long ap1 = (long)(((ulong_)hi1 << 32) | lo1);

    // ---- GEMM2: dz += phi @ Wz ----
    __builtin_amdgcn_s_setprio(1);
#pragma unroll
    for (int nt = 0; nt < 4; ++nt) {
      acc[0][nt] = __builtin_amdgcn_mfma_f32_16x16x32_fp8_fp8(ap0, Abb[par][nt], acc[0][nt], 0, 0, 0);
      acc[1][nt] = __builtin_amdgcn_mfma_f32_16x16x32_fp8_fp8(ap1, Abb[par][nt], acc[1][nt], 0, 0, 0);
    }
    __builtin_amdgcn_s_setprio(0);
  }
#undef LOADB

  // ---- dl partials: sum over the 4 quads holding the same row ----
#pragma unroll
  for (int mt = 0; mt < 2; ++mt) {
    float v = dl[mt];
    v += __shfl_xor(v, 16);
    v += __shfl_xor(v, 32);
    if (quad == 0) dlr[ws][mt * 16 + lrow] = v;
  }

  // ---- dz combine across the 4 c-split waves ----
  for (int s = 0; s < 4; ++s) {
    __syncthreads();
    if (ws == s) {
#pragma unroll
      for (int mt = 0; mt < 2; ++mt)
#pragma unroll
        for (int nt = 0; nt < 4; ++nt)
#pragma unroll
          for (int i = 0; i < 4; ++i) {
            int r = mt * 16 + quad * 4 + i;
            int d = nt * 16 + lrow;
            if (s == 0) eps[r * 68 + d] = acc[mt][nt][i];
            else        eps[r * 68 + d] += acc[mt][nt][i];
          }
    }
  }
  __syncthreads();

  // ---- outputs ----
  {
    int r = tid >> 3, d0 = (tid & 7) * 8;   // 256 thr x 8 floats = 32x64
    float4 e0 = *(const float4*)&eps[r * 68 + d0];
    float4 e1 = *(const float4*)&eps[r * 68 + d0 + 4];
    float4 bv0 = *(const float4*)&bias[d0];
    float4 bv1 = *(const float4*)&bias[d0 + 4];
    float4 o0, o1;
    o0.x = e0.x + bv0.x; o0.y = e0.y + bv0.y; o0.z = e0.z + bv0.z; o0.w = e0.w + bv0.w;
    o1.x = e1.x + bv1.x; o1.y = e1.y + bv1.y; o1.z = e1.z + bv1.z; o1.w = e1.w + bv1.w;
    *(float4*)&out[(size_t)(b0 + r) * DD + d0]     = o0;
    *(float4*)&out[(size_t)(b0 + r) * DD + d0 + 4] = o1;
  }
  if (tid < 32) {
    float s = dlr[0][tid] + dlr[1][tid] + dlr[2][tid] + dlr[3][tid];
    out[(size_t)BB * DD + b0 + tid] = 2.f * s;
  }
}

// ---------------------------------------------------------------------------
extern "C" void kernel_launch(void* const* d_in, const int* in_sizes, int n_in,
                              void* d_out, int out_size, void* d_ws, size_t ws_size,
                              hipStream_t stream)
{
  const float* t   = (const float*)d_in[0];
  const float* z   = (const float*)d_in[1];
  // d_in[2] = logp_z (unused)
  const float* cz  = (const float*)d_in[3];
  const float* lsz = (const float*)d_in[4];
  const float* ct  = (const float*)d_in[5];
  const float* lst = (const float*)d_in[6];
  const float* W   = (const float*)d_in[7];
  float* out = (float*)d_out;
  float* ws  = (float*)d_ws;

  float*  bias = ws + BIAS_OFF;
  float*  il2a = ws + IL2_OFF;
  float*  a0a  = ws + A0_OFF;
  float*  niqa = ws + NIQ_OFF;
  uchar*  czp  = (uchar*)(ws + CZP_OFF);
  uchar*  wzp  = (uchar*)(ws + WZP_OFF);
  uchar*  wzbp8 = (uchar*)(ws + WZBP_OFF);
  float*  part = ws + PART_OFF;

  k_wt1<<<dim3(9, 64, 4), 256, 0, stream>>>(t, ct, lst, W, part);
  k_prep2<<<dim3(256), 256, 0, stream>>>(part, cz, lsz, bias,
                                         il2a, a0a, niqa,
                                         czp, wzp, wzbp8);
  k_fused<<<dim3(BB / 32), 256, 0, stream>>>(z, czp, wzp, wzbp8,
                                             il2a, a0a, niqa, bias, out);
}